// Round 16
// baseline (446.546 us; speedup 1.0000x reference)
//
#include <hip/hip_runtime.h>

// Problem constants (fixed shapes for this identifier)
#define N_ROWS 16384   // b*n = 4*4096
#define DIM    512
#define KCODES 8192

#define DECAYF 0.8f
#define RESIDF 0.2f
#define EPSF   1e-5f
#define THRGAP 0.15f   // refine-skip threshold (~8 sigma of 1-pass fp16 score noise)
#define NSPLIT 32      // col-blocks (256 cols each)

// ---- d_out float offsets (outputs concatenated in return order) ----
#define OQ 0            // quantize_st    [16384,512]  (scratch: Xs fp16)
#define OI 8388608      // ind            [16384]
#define OL 8404992      // commit_loss    [1]
#define OE 8404993      // new_embed      [8192,512]   (scratch: Es fp16 + pt1 + pt2)
#define OC 12599297     // new_cluster    [8192]
#define OA 12607489     // new_embed_avg  [8192,512]

// ---- workspace offsets (float-indexed; int arrays alias) ----
#define WS_E2     0                    // [8192] float
#define WS_BINS   8192                 // [8192] int counts (zeroed each call)
#define WS_LOSS   16384                // [1] float
#define WS_TOTAL  16385                // [1] float
#define WS_IND    16400                // [16384] int final index
#define WS_OFF    (WS_IND+16384)       // [8192] int exclusive offsets
#define WS_WOFF   (WS_OFF+8192)        // [8192] int working offsets (scatter)
#define WS_SORTED (WS_WOFF+8192)       // [16384] int row ids sorted by code

typedef _Float16 half8 __attribute__((ext_vector_type(8)));
typedef float f32x4 __attribute__((ext_vector_type(4)));

__device__ __forceinline__ void ldg_lds16(const char* g, char* l) {
    __builtin_amdgcn_global_load_lds(
        (const __attribute__((address_space(1))) void*)g,
        (__attribute__((address_space(3))) void*)l, 16, 0, 0);
}

// monotonic (score,idx) -> u64: order-preserving, ties break to smaller idx
__device__ __forceinline__ unsigned long long enc64(float v, unsigned idx) {
    unsigned int b = __float_as_uint(v);
    b ^= (unsigned)((int)b >> 31) | 0x80000000u;
    return ((unsigned long long)b << 13) | idx;
}
__device__ __forceinline__ float dec64(unsigned long long u) {
    unsigned int eb = (unsigned int)(u >> 13);
    unsigned int b = (eb & 0x80000000u) ? (eb ^ 0x80000000u) : ~eb;
    return __uint_as_float(b);
}

// ======= kernel 0: fused x->Xs fp16 (blocks 0..4095) and embed->Es fp16 + e2 =======
__global__ void convxe_kernel(const float* __restrict__ x, const float* __restrict__ e,
                              _Float16* __restrict__ xs, _Float16* __restrict__ es,
                              float* __restrict__ ws) {
    if (blockIdx.x < 4096) {
        int i = blockIdx.x * 256 + threadIdx.x;
        int row = i >> 6;
        int c8 = (i & 63) * 8;
        const float4* g = (const float4*)(x + row * DIM + c8);
        float4 v0 = g[0], v1 = g[1];
        float vv[8] = {v0.x, v0.y, v0.z, v0.w, v1.x, v1.y, v1.z, v1.w};
        half8 hv;
#pragma unroll
        for (int j = 0; j < 8; ++j) hv[j] = (_Float16)vv[j];
        *(half8*)(xs + row * DIM + c8) = hv;
    } else {
        int i = (blockIdx.x - 4096) * 256 + threadIdx.x;   // one wave per code row
        int row = i >> 6;
        int lane = threadIdx.x & 63;
        int c8 = (i & 63) * 8;
        const float4* g = (const float4*)(e + row * DIM + c8);
        float4 v0 = g[0], v1 = g[1];
        float vv[8] = {v0.x, v0.y, v0.z, v0.w, v1.x, v1.y, v1.z, v1.w};
        half8 hv;
        float s = 0.f;
#pragma unroll
        for (int j = 0; j < 8; ++j) { hv[j] = (_Float16)vv[j]; s += vv[j] * vv[j]; }
        *(half8*)(es + row * DIM + c8) = hv;
#pragma unroll
        for (int off = 32; off; off >>= 1) s += __shfl_xor(s, off);
        if (lane == 0) ws[WS_E2 + row] = s;
    }
}

// ============ kernel 1: 8-phase 256x256 fp16 MFMA distance GEMM ============
// R15 race fixed: the vmcnt that drains step k+1's inputs now sits at k.f3 PRE-barrier
// (not at k+1.f0). Barrier-pair(f3) publishes "all waves drained A(k+1),B(k+1)" ->
// k+1's PRE-barrier ds_reads are race-free (global_load_lds completion is per-wave
// vmcnt; only a barrier after every wave's vmcnt makes peer data visible). This is
// m201's actual discipline: counted vmcnt a phase EARLIER than the reads it protects.
// Phase = [ds_read frags | stage | (f3: vmcnt) | barrier | lgkm(0) | MFMA x16 | barrier].
// Drain accounting at k.f3: outstanding = B(k+1):4 + A(k+1):4 + B(k+2):4 loads;
// vmcnt(4) keeps exactly B(k+2). k=6 -> vmcnt(0) (no B(8)); k=7 -> none.
// Prologue: 6 stages + vmcnt(4) + barrier covers step 0. Slot-write safety = R14 proof.
__global__ __launch_bounds__(512, 2) void dist_kernel(
        const _Float16* __restrict__ xs, const _Float16* __restrict__ es,
        const float* __restrict__ ws,
        unsigned long long* __restrict__ pt1, unsigned long long* __restrict__ pt2) {
    __shared__ __align__(16) char smem[131072];            // 2 parity x 4 slots x 16KB
    __shared__ __align__(16) unsigned long long mbuf[4][256][2];

    const int tid = threadIdx.x, wid = tid >> 6, lane = tid & 63;
    const int xcd = blockIdx.x & 7, i = blockIdx.x >> 3;
    const int rt = xcd * 8 + (i & 7);       // 0..63 ; XCD owns rows [xcd*2048,+2048)
    const int ct = i >> 3;                  // 0..31
    const int rowbase = rt * 256, colbase = ct * 256;

    const int wm = wid >> 2, wn = wid & 3, wn1 = wn & 1;
    const int l15 = lane & 15, q = lane >> 4;

    // fragment LDS offsets (swizzled): chunk = (kh*4+q) ^ (l15&7)
    int chnk[2];
#pragma unroll
    for (int kh = 0; kh < 2; ++kh) chnk[kh] = (((kh * 4 + q) ^ (l15 & 7)) << 4);
    const int aoffb0 = l15 * 128 + chnk[0], aoffb1 = l15 * 128 + chnk[1];
    int boffs[8];
#pragma unroll
    for (int n = 0; n < 4; ++n)
#pragma unroll
        for (int kh = 0; kh < 2; ++kh)
            boffs[n * 2 + kh] = (wn1 * 64 + n * 16 + l15) * 128 + chnk[kh];

    // staging source pre-swizzle: logical chunk = (tid&7) ^ ((tid>>3)&7)
    const unsigned srcoff = ((unsigned)(tid >> 3) << 10)
                          + ((unsigned)((tid & 7) ^ ((tid >> 3) & 7)) << 4);
    const char* xb = (const char*)xs;
    const char* eb = (const char*)es;

#define STAGE_A(kp_, h_) { \
    const int sb_ = (((kp_) & 1) << 16) + ((h_) << 14); \
    _Pragma("unroll") \
    for (int c = 0; c < 2; ++c) \
        ldg_lds16(xb + (((unsigned)(rowbase + (h_) * 128 + c * 64)) << 10) + srcoff \
                     + ((unsigned)(kp_) << 7), \
                  smem + sb_ + c * 8192 + (wid << 10)); }
#define STAGE_B(kp_, h_) { \
    const int sb_ = (((kp_) & 1) << 16) + ((2 + (h_)) << 14); \
    _Pragma("unroll") \
    for (int c = 0; c < 2; ++c) \
        ldg_lds16(eb + (((unsigned)(colbase + (h_) * 128 + c * 64)) << 10) + srcoff \
                     + ((unsigned)(kp_) << 7), \
                  smem + sb_ + c * 8192 + (wid << 10)); }

    f32x4 acc[8][4];
#pragma unroll
    for (int m = 0; m < 8; ++m)
#pragma unroll
        for (int n = 0; n < 4; ++n) acc[m][n] = (f32x4){0.f, 0.f, 0.f, 0.f};

    // prologue: step-0 all 4 half-tiles + B of step 1; drain step-0 inputs; publish
    STAGE_B(0, 0); STAGE_B(0, 1); STAGE_A(0, 1); STAGE_A(0, 0);
    STAGE_B(1, 0); STAGE_B(1, 1);
    asm volatile("s_waitcnt vmcnt(4)" ::: "memory");   // keep B(1); drain A(0),B(0)
    __builtin_amdgcn_s_barrier();

    half8 bh[8];
#define MFMA16(F_, a0_, a1_, a2_, a3_) { \
    __builtin_amdgcn_s_setprio(1); \
    _Pragma("unroll") \
    for (int n = 0; n < 4; ++n) { \
        acc[2*(F_)][n]   = __builtin_amdgcn_mfma_f32_16x16x32_f16(a0_, bh[2*n],   acc[2*(F_)][n],   0, 0, 0); \
        acc[2*(F_)][n]   = __builtin_amdgcn_mfma_f32_16x16x32_f16(a1_, bh[2*n+1], acc[2*(F_)][n],   0, 0, 0); \
        acc[2*(F_)+1][n] = __builtin_amdgcn_mfma_f32_16x16x32_f16(a2_, bh[2*n],   acc[2*(F_)+1][n], 0, 0, 0); \
        acc[2*(F_)+1][n] = __builtin_amdgcn_mfma_f32_16x16x32_f16(a3_, bh[2*n+1], acc[2*(F_)+1][n], 0, 0, 0); \
    } \
    __builtin_amdgcn_s_setprio(0); }

#pragma unroll 1
    for (int k = 0; k < 8; ++k) {
        const int p = (k & 1) << 16;
        const char* Ab = smem + p + (wm << 14);
        const char* Bb = smem + p + ((2 + (wn >> 1)) << 14);
        // ---- f0: reads drained by (k-1).f3 vmcnt + barrier ----
        {
#pragma unroll
            for (int z = 0; z < 8; ++z) bh[z] = *(const half8*)(Bb + boffs[z]);
            half8 a0_ = *(const half8*)(Ab + 0 * 2048 + aoffb0);
            half8 a1_ = *(const half8*)(Ab + 0 * 2048 + aoffb1);
            half8 a2_ = *(const half8*)(Ab + 1 * 2048 + aoffb0);
            half8 a3_ = *(const half8*)(Ab + 1 * 2048 + aoffb1);
            if (k < 7) STAGE_A(k + 1, 1);
            __builtin_amdgcn_sched_barrier(0);
            __builtin_amdgcn_s_barrier();
            asm volatile("s_waitcnt lgkmcnt(0)" ::: "memory");
            __builtin_amdgcn_sched_barrier(0);
            MFMA16(0, a0_, a1_, a2_, a3_);
        }
        __builtin_amdgcn_s_barrier();
        // ---- f1 ----
        {
            half8 a0_ = *(const half8*)(Ab + 2 * 2048 + aoffb0);
            half8 a1_ = *(const half8*)(Ab + 2 * 2048 + aoffb1);
            half8 a2_ = *(const half8*)(Ab + 3 * 2048 + aoffb0);
            half8 a3_ = *(const half8*)(Ab + 3 * 2048 + aoffb1);
            if (k < 7) STAGE_A(k + 1, 0);
            __builtin_amdgcn_sched_barrier(0);
            __builtin_amdgcn_s_barrier();
            asm volatile("s_waitcnt lgkmcnt(0)" ::: "memory");
            __builtin_amdgcn_sched_barrier(0);
            MFMA16(1, a0_, a1_, a2_, a3_);
        }
        __builtin_amdgcn_s_barrier();
        // ---- f2 ----
        {
            half8 a0_ = *(const half8*)(Ab + 4 * 2048 + aoffb0);
            half8 a1_ = *(const half8*)(Ab + 4 * 2048 + aoffb1);
            half8 a2_ = *(const half8*)(Ab + 5 * 2048 + aoffb0);
            half8 a3_ = *(const half8*)(Ab + 5 * 2048 + aoffb1);
            if (k < 6) STAGE_B(k + 2, 0);
            __builtin_amdgcn_sched_barrier(0);
            __builtin_amdgcn_s_barrier();
            asm volatile("s_waitcnt lgkmcnt(0)" ::: "memory");
            __builtin_amdgcn_sched_barrier(0);
            MFMA16(2, a0_, a1_, a2_, a3_);
        }
        __builtin_amdgcn_s_barrier();
        // ---- f3: counted vmcnt HERE drains step k+1's inputs; barrier publishes ----
        {
            half8 a0_ = *(const half8*)(Ab + 6 * 2048 + aoffb0);
            half8 a1_ = *(const half8*)(Ab + 6 * 2048 + aoffb1);
            half8 a2_ = *(const half8*)(Ab + 7 * 2048 + aoffb0);
            half8 a3_ = *(const half8*)(Ab + 7 * 2048 + aoffb1);
            if (k < 6) STAGE_B(k + 2, 1);
            if (k < 6)      { asm volatile("s_waitcnt vmcnt(4)" ::: "memory"); }
            else if (k == 6){ asm volatile("s_waitcnt vmcnt(0)" ::: "memory"); }
            __builtin_amdgcn_sched_barrier(0);
            __builtin_amdgcn_s_barrier();
            asm volatile("s_waitcnt lgkmcnt(0)" ::: "memory");
            __builtin_amdgcn_sched_barrier(0);
            MFMA16(3, a0_, a1_, a2_, a3_);
        }
        __builtin_amdgcn_s_barrier();
    }
#undef MFMA16
#undef STAGE_A
#undef STAGE_B

    // ---- epilogue (once per block): per-row top-2 over this 256-col tile ----
    float e2v[4];
#pragma unroll
    for (int n = 0; n < 4; ++n) e2v[n] = ws[WS_E2 + colbase + wn * 64 + n * 16 + l15];
    const unsigned cb0 = (unsigned)(colbase + wn * 64 + l15);

#pragma unroll
    for (int m = 0; m < 8; ++m) {
#pragma unroll
        for (int j = 0; j < 4; ++j) {
            unsigned long long u0 = enc64(fmaf(-2.f, acc[m][0][j], e2v[0]), cb0);
            unsigned long long u1 = enc64(fmaf(-2.f, acc[m][1][j], e2v[1]), cb0 + 16);
            unsigned long long u2 = enc64(fmaf(-2.f, acc[m][2][j], e2v[2]), cb0 + 32);
            unsigned long long u3 = enc64(fmaf(-2.f, acc[m][3][j], e2v[3]), cb0 + 48);
            unsigned long long a1 = u0 < u1 ? u0 : u1, a2 = u0 < u1 ? u1 : u0;
            unsigned long long b1 = u2 < u3 ? u2 : u3, b2 = u2 < u3 ? u3 : u2;
            unsigned long long t1, t2;
            if (a1 < b1) { t1 = a1; t2 = a2 < b1 ? a2 : b1; }
            else         { t1 = b1; t2 = b2 < a1 ? b2 : a1; }
#pragma unroll
            for (int mk = 1; mk <= 8; mk <<= 1) {
                unsigned long long o1 = __shfl_xor(t1, mk);
                unsigned long long o2 = __shfl_xor(t2, mk);
                if (o1 < t1) { t2 = t1 < o2 ? t1 : o2; t1 = o1; }
                else         { t2 = o1 < t2 ? o1 : t2; }
            }
            if (l15 == 0) {
                int rowl = wm * 128 + m * 16 + q * 4 + j;
                mbuf[wn][rowl][0] = t1;
                mbuf[wn][rowl][1] = t2;
            }
        }
    }
    __syncthreads();
    if (tid < 256) {   // combine 4 wn-slices -> per-(row, col-block) top-2
        unsigned long long t1 = ~0ull, t2 = ~0ull;
#pragma unroll
        for (int w = 0; w < 4; ++w) {
            unsigned long long v1 = mbuf[w][tid][0], v2 = mbuf[w][tid][1];
            if (v1 < t1) { t2 = t1 < v2 ? t1 : v2; t1 = v1; }
            else         { t2 = v1 < t2 ? v1 : t2; }
        }
        pt1[ct * N_ROWS + rowbase + tid] = t1;
        pt2[ct * N_ROWS + rowbase + tid] = t2;
    }
}

// ====== kernel 2: assign = fused merge + gap-gated fp64 refine + quantize + loss + bins ======
__global__ void assign_kernel(const float* __restrict__ x, const float* __restrict__ embed,
                              const unsigned long long* __restrict__ pt1,
                              const unsigned long long* __restrict__ pt2,
                              float* __restrict__ ws, float* __restrict__ out) {
    int tid = threadIdx.x, wid = tid >> 6, lane = tid & 63;
    int row = blockIdx.x * 4 + wid;                 // one wave per row
    const float* xr = x + row * DIM + lane * 8;
    float4 xv0 = *(const float4*)xr;
    float4 xv1 = *(const float4*)(xr + 4);
    float xv[8] = {xv0.x, xv0.y, xv0.z, xv0.w, xv1.x, xv1.y, xv1.z, xv1.w};

    // fused merge: 32 col-block partials x2 -> global top-4 (all lanes redundantly)
    unsigned long long t[4] = {~0ull, ~0ull, ~0ull, ~0ull};
#pragma unroll 4
    for (int cb = 0; cb < NSPLIT; ++cb) {
        unsigned long long a = pt1[cb * N_ROWS + row];
        unsigned long long b = pt2[cb * N_ROWS + row];
#pragma unroll
        for (int z = 0; z < 2; ++z) {
            unsigned long long v = z ? b : a;
            if (v < t[3]) {
                t[3] = v;
                if (t[3] < t[2]) { unsigned long long y = t[2]; t[2] = t[3]; t[3] = y;
                    if (t[2] < t[1]) { y = t[1]; t[1] = t[2]; t[2] = y;
                        if (t[1] < t[0]) { y = t[0]; t[0] = t[1]; t[1] = y; } } }
            }
        }
    }
    float gap = dec64(t[1]) - dec64(t[0]);
    int besti = (int)(t[0] & 0x1FFFu);
    if (gap <= THRGAP) {   // rare: exact fp64 over 4 candidates
        double bestv = 1e300; besti = 0x7fffffff;
#pragma unroll
        for (int s = 0; s < 4; ++s) {
            int ci = (int)(t[s] & 0x1FFFu);
            const float* er = embed + ci * DIM + lane * 8;
            double d = 0.0;
#pragma unroll
            for (int u = 0; u < 8; ++u) {
                double diff = (double)xv[u] - (double)er[u];
                d += diff * diff;
            }
#pragma unroll
            for (int off = 32; off; off >>= 1) d += __shfl_xor(d, off);
            if (d < bestv || (d == bestv && ci < besti)) { bestv = d; besti = ci; }
        }
    }

    const float* er = embed + besti * DIM + lane * 8;
    float4 q0 = *(const float4*)er;
    float4 q1 = *(const float4*)(er + 4);
    float qv[8] = {q0.x, q0.y, q0.z, q0.w, q1.x, q1.y, q1.z, q1.w};
    float st[8], ls = 0.f;
#pragma unroll
    for (int u = 0; u < 8; ++u) {
        float d = qv[u] - xv[u];
        st[u] = xv[u] + d;          // match ref rounding: x + (q - x)
        ls += d * d;
    }
    float* oq = out + OQ + row * DIM + lane * 8;
    *(float4*)oq       = (float4){st[0], st[1], st[2], st[3]};
    *(float4*)(oq + 4) = (float4){st[4], st[5], st[6], st[7]};
#pragma unroll
    for (int off = 32; off; off >>= 1) ls += __shfl_xor(ls, off);
    __shared__ float lsb[4];
    if (lane == 0) {
        lsb[wid] = ls;
        out[OI + row] = (float)besti;
        ((int*)ws)[WS_IND + row] = besti;
        atomicAdd((int*)ws + WS_BINS + besti, 1);
    }
    __syncthreads();
    if (tid == 0) atomicAdd(ws + WS_LOSS, lsb[0] + lsb[1] + lsb[2] + lsb[3]);
}

// ===== kernel 3: fused cluster + scan (single block): ncs, total, loss, offsets =====
__global__ void scan_kernel(const float* __restrict__ cs, float* __restrict__ ws,
                            float* __restrict__ out) {
    __shared__ int lds[256];
    __shared__ float fl[256];
    int tid = threadIdx.x;
    const int* bins = (const int*)ws + WS_BINS;
    int* off  = (int*)ws + WS_OFF;
    int* woff = (int*)ws + WS_WOFF;
    int base = tid * 32;
    int local[32], s = 0; float sn = 0.f;
#pragma unroll
    for (int j = 0; j < 32; ++j) {
        int b = bins[base + j];
        local[j] = b; s += b;
        float ncs = DECAYF * cs[base + j] + RESIDF * (float)b;
        out[OC + base + j] = ncs;
        sn += ncs;
    }
    lds[tid] = s; fl[tid] = sn;
    __syncthreads();
    for (int o = 1; o < 256; o <<= 1) {   // Hillis-Steele inclusive scan + float total
        int v = (tid >= o) ? lds[tid - o] : 0;
        float f = (tid >= o) ? fl[tid - o] : 0.f;
        __syncthreads();
        lds[tid] += v; fl[tid] += f;
        __syncthreads();
    }
    int run = lds[tid] - s;   // exclusive
#pragma unroll
    for (int j = 0; j < 32; ++j) {
        off[base + j] = run; woff[base + j] = run;
        run += local[j];
    }
    if (tid == 0) {
        ws[WS_TOTAL] = fl[255];
        out[OL] = ws[WS_LOSS] / 8388608.0f;
    }
}

// ===== kernel 4: scatter row ids into code-sorted order (64 blocks, global atomics) =====
__global__ void scatter_kernel(float* __restrict__ ws) {
    int row = blockIdx.x * 256 + threadIdx.x;
    int ind = ((const int*)ws)[WS_IND + row];
    int pos = atomicAdd((int*)ws + WS_WOFF + ind, 1);
    ((int*)ws)[WS_SORTED + pos] = row;
}

// ===== kernel 5: segmented EMA sum + smoothed divide (one wave per code) =====
__global__ void ema_kernel(const float* __restrict__ x, const float* __restrict__ avg,
                           const float* __restrict__ ws, float* __restrict__ out) {
    int tid = threadIdx.x, wid = tid >> 6, lane = tid & 63;
    int k = blockIdx.x * 4 + wid;
    int cnt   = ((const int*)ws)[WS_BINS + k];
    int start = ((const int*)ws)[WS_OFF + k];
    const int c8 = lane * 8;
    float sum[8] = {0.f, 0.f, 0.f, 0.f, 0.f, 0.f, 0.f, 0.f};
    for (int c = 0; c < cnt; ++c) {
        int row = ((const int*)ws)[WS_SORTED + start + c];
        const float* xr = x + row * DIM + c8;
        float4 v0 = *(const float4*)xr;
        float4 v1 = *(const float4*)(xr + 4);
        sum[0] += v0.x; sum[1] += v0.y; sum[2] += v0.z; sum[3] += v0.w;
        sum[4] += v1.x; sum[5] += v1.y; sum[6] += v1.z; sum[7] += v1.w;
    }
    const float* ar = avg + k * DIM + c8;
    float4 a0 = *(const float4*)ar;
    float4 a1 = *(const float4*)(ar + 4);
    float av[8] = {a0.x, a0.y, a0.z, a0.w, a1.x, a1.y, a1.z, a1.w};
    float total = ws[WS_TOTAL];
    float ncs = out[OC + k];
    float sm = (ncs + EPSF) / (total + (float)KCODES * EPSF) * total;
    float* oa = out + OA + k * DIM + c8;   // 4B-aligned regions -> scalar stores
    float* oe = out + OE + k * DIM + c8;
#pragma unroll
    for (int u = 0; u < 8; ++u) {
        float na = DECAYF * av[u] + RESIDF * sum[u];
        oa[u] = na;
        oe[u] = na / sm;
    }
}

extern "C" void kernel_launch(void* const* d_in, const int* in_sizes, int n_in,
                              void* d_out, int out_size, void* d_ws, size_t ws_size,
                              hipStream_t stream) {
    const float* x     = (const float*)d_in[0];
    const float* embed = (const float*)d_in[1];
    const float* cs    = (const float*)d_in[2];
    const float* avg   = (const float*)d_in[3];
    float* out = (float*)d_out;
    float* ws  = (float*)d_ws;

    // scratch inside d_out (consumed before final writes):
    //   Xs (16.8MB) in OQ; OE region holds Es (8.39MB) + pt1 (4MB) + pt2 (4MB);
    //   assign consumes pt1/pt2 before ema writes OE.
    _Float16* xs = (_Float16*)((char*)d_out + (size_t)OQ * 4);
    char* esb = (char*)d_out + (((size_t)OE * 4 + 15) & ~(size_t)15);
    _Float16* es = (_Float16*)esb;
    unsigned long long* pt1 = (unsigned long long*)(esb + (size_t)KCODES * DIM * 2);
    unsigned long long* pt2 = pt1 + (size_t)NSPLIT * N_ROWS;

    // zero bins + loss + total each call
    hipMemsetAsync((char*)d_ws + WS_BINS * 4, 0, (8192 + 2) * 4, stream);

    convxe_kernel <<<6144, 256, 0, stream>>>(x, embed, xs, es, ws);
    dist_kernel   <<<2048, 512, 0, stream>>>(xs, es, ws, pt1, pt2);
    assign_kernel <<<N_ROWS / 4, 256, 0, stream>>>(x, embed, pt1, pt2, ws, out);
    scan_kernel   <<<1, 256, 0, stream>>>(cs, ws, out);
    scatter_kernel<<<N_ROWS / 256, 256, 0, stream>>>(ws);
    ema_kernel    <<<KCODES / 4, 256, 0, stream>>>(x, avg, ws, out);
}

// Round 17
// 379.489 us; speedup vs baseline: 1.1767x; 1.1767x over previous
//
#include <hip/hip_runtime.h>

// Problem constants (fixed shapes for this identifier)
#define N_ROWS 16384   // b*n = 4*4096
#define DIM    512
#define KCODES 8192

#define DECAYF 0.8f
#define RESIDF 0.2f
#define EPSF   1e-5f
#define THRGAP 0.15f   // refine-skip threshold (~8 sigma of 1-pass fp16 score noise)
#define NSPLIT 8       // col-groups per row (1024 cols each)

// ---- d_out float offsets (outputs concatenated in return order) ----
#define OQ 0            // quantize_st    [16384,512]  (scratch: Xs fp16)
#define OI 8388608      // ind            [16384]
#define OL 8404992      // commit_loss    [1]
#define OE 8404993      // new_embed      [8192,512]   (scratch: Es fp16 + pt1)
#define OC 12599297     // new_cluster    [8192]
#define OA 12607489     // new_embed_avg  [8192,512]   (scratch: pt2)

// ---- workspace offsets (float-indexed; int arrays alias) ----
#define WS_E2     0                    // [8192] float
#define WS_BINS   8192                 // [8192] int counts (zeroed each call)
#define WS_LOSS   16384                // [1] float
#define WS_TOTAL  16385                // [1] float
#define WS_IND    16400                // [16384] int final index
#define WS_OFF    (WS_IND+16384)       // [8192] int exclusive offsets
#define WS_WOFF   (WS_OFF+8192)        // [8192] int working offsets (scatter)
#define WS_SORTED (WS_WOFF+8192)       // [16384] int row ids sorted by code

typedef _Float16 half8 __attribute__((ext_vector_type(8)));
typedef float f32x4 __attribute__((ext_vector_type(4)));

__device__ __forceinline__ void ldg_lds16(const char* g, char* l) {
    __builtin_amdgcn_global_load_lds(
        (const __attribute__((address_space(1))) void*)g,
        (__attribute__((address_space(3))) void*)l, 16, 0, 0);
}

// monotonic (score,idx) -> u64: order-preserving, ties break to smaller idx
__device__ __forceinline__ unsigned long long enc64(float v, unsigned idx) {
    unsigned int b = __float_as_uint(v);
    b ^= (unsigned)((int)b >> 31) | 0x80000000u;
    return ((unsigned long long)b << 13) | idx;
}
__device__ __forceinline__ float dec64(unsigned long long u) {
    unsigned int eb = (unsigned int)(u >> 13);
    unsigned int b = (eb & 0x80000000u) ? (eb ^ 0x80000000u) : ~eb;
    return __uint_as_float(b);
}

// ======= kernel 0: fused x->Xs fp16 (blocks 0..4095) and embed->Es fp16 + e2 =======
__global__ void convxe_kernel(const float* __restrict__ x, const float* __restrict__ e,
                              _Float16* __restrict__ xs, _Float16* __restrict__ es,
                              float* __restrict__ ws) {
    if (blockIdx.x < 4096) {
        int i = blockIdx.x * 256 + threadIdx.x;
        int row = i >> 6;
        int c8 = (i & 63) * 8;
        const float4* g = (const float4*)(x + row * DIM + c8);
        float4 v0 = g[0], v1 = g[1];
        float vv[8] = {v0.x, v0.y, v0.z, v0.w, v1.x, v1.y, v1.z, v1.w};
        half8 hv;
#pragma unroll
        for (int j = 0; j < 8; ++j) hv[j] = (_Float16)vv[j];
        *(half8*)(xs + row * DIM + c8) = hv;
    } else {
        int i = (blockIdx.x - 4096) * 256 + threadIdx.x;   // one wave per code row
        int row = i >> 6;
        int lane = threadIdx.x & 63;
        int c8 = (i & 63) * 8;
        const float4* g = (const float4*)(e + row * DIM + c8);
        float4 v0 = g[0], v1 = g[1];
        float vv[8] = {v0.x, v0.y, v0.z, v0.w, v1.x, v1.y, v1.z, v1.w};
        half8 hv;
        float s = 0.f;
#pragma unroll
        for (int j = 0; j < 8; ++j) { hv[j] = (_Float16)vv[j]; s += vv[j] * vv[j]; }
        *(half8*)(es + row * DIM + c8) = hv;
#pragma unroll
        for (int off = 32; off; off >>= 1) s += __shfl_xor(s, off);
        if (lane == 0) ws[WS_E2 + row] = s;
    }
}

// ============ kernel 1: 1-pass fp16 MFMA distance GEMM, 256-col windows, UNPINNED ============
// R12's exact structure (proven 228us) minus the schedule pins: removed the
// sched_barrier(0) between STAGE and the MFMA cluster and the setprio pair. Both are
// side-effecting scheduling fences that forced "all 12 ds_reads complete, then all 32
// MFMAs" (phase alternation -> MfmaUtil pinned 21-26% across R5-R16). With them gone
// the compiler emits counted lgkmcnt so MFMAs start as soon as their fragments arrive
// (m97's 37%-util mechanism; m141 showed pinning costs 874->510 TF).
// Correctness unchanged: first sched_barrier still pins reads below the barrier;
// STAGE loads cannot sink past the next iteration's vmcnt asm (memory clobber);
// MFMA/read ordering enforced by data dependence.
__global__ __launch_bounds__(256, 2) void dist_kernel(
        const _Float16* __restrict__ xs, const _Float16* __restrict__ es,
        const float* __restrict__ ws,
        unsigned long long* __restrict__ pt1, unsigned long long* __restrict__ pt2) {
    __shared__ __align__(16) char smem[73728];   // 3 x (8KB A | 16KB B)
    __shared__ __align__(16) float e2s[1024];

    const int tid = threadIdx.x, wid = tid >> 6, lane = tid & 63;
    const int xcd = blockIdx.x & 7, i = blockIdx.x >> 3;
    const int rtl = i & 15;                 // row-tile within XCD slice
    const int cg  = i >> 4;                 // 0..7 col-group (1024 cols)
    const int rowbase = xcd * 2048 + rtl * 128;
    const int colsplit = cg * 1024;

    const int wm = wid >> 1, wn = wid & 1;
    const int l15 = lane & 15, q = lane >> 4;
    const int swz = ((q ^ ((l15 >> 1) & 3)) << 4);

    int aoff[4], boff[8];
#pragma unroll
    for (int m = 0; m < 4; ++m) aoff[m] = (wm * 64 + m * 16 + l15) * 64 + swz;
#pragma unroll
    for (int n = 0; n < 8; ++n) boff[n] = 8192 + (wn * 128 + n * 16 + l15) * 64 + swz;

    unsigned gA[2], gB[4];
#pragma unroll
    for (int c = 0; c < 2; ++c) {
        int p = c * 4096 + tid * 16;
        int r = p >> 6, sp = (p >> 4) & 3;
        int sl = sp ^ ((r >> 1) & 3);
        gA[c] = (unsigned)(rowbase + r) * 1024u + (unsigned)(sl * 16);
    }
#pragma unroll
    for (int c = 0; c < 4; ++c) {
        int p = c * 4096 + tid * 16;
        int r = p >> 6, sp = (p >> 4) & 3;   // r in [0,256) = col within window
        int sl = sp ^ ((r >> 1) & 3);
        gB[c] = (unsigned)(colsplit + r) * 1024u + (unsigned)(sl * 16);
    }
    const char* xb = (const char*)xs;
    const char* eb = (const char*)es;

    // e2 -> LDS stash; sync BEFORE prologue stages
    {
        float4 v = *(const float4*)(ws + WS_E2 + colsplit + tid * 4);
        *(float4*)(e2s + tid * 4) = v;
    }
    __syncthreads();

    // running per-row top-2: b1<=b2, cp = c1 | (c2<<16); rows r = m*4+j
    float b1[16], b2[16]; unsigned cp[16];
#pragma unroll
    for (int r = 0; r < 16; ++r) { b1[r] = 3.4e38f; b2[r] = 3.4e38f; cp[r] = 0xFFFFFFFFu; }

    f32x4 acc[4][8];
#pragma unroll
    for (int m = 0; m < 4; ++m)
#pragma unroll
        for (int n = 0; n < 8; ++n) acc[m][n] = (f32x4){0.f, 0.f, 0.f, 0.f};

    // STAGE step gs into buffer base sb: A 2 chunks + B 4 chunks (6 ldg/wave)
#define STAGE(gs_, sb_) { \
    const unsigned koff = ((unsigned)((gs_) & 15)) << 6; \
    const char* ebw = eb + ((size_t)((gs_) >> 4) << 18); \
    _Pragma("unroll") \
    for (int c = 0; c < 2; ++c) \
        ldg_lds16(xb + gA[c] + koff, smem + (sb_) + c * 4096 + (wid << 10)); \
    _Pragma("unroll") \
    for (int c = 0; c < 4; ++c) \
        ldg_lds16(ebw + gB[c] + koff, smem + (sb_) + 8192 + c * 4096 + (wid << 10)); }

#define FOLD(w_) { \
    const int w = (w_); \
    float e2v[8]; \
    _Pragma("unroll") \
    for (int n = 0; n < 8; ++n) e2v[n] = e2s[w * 256 + wn * 128 + n * 16 + l15]; \
    const unsigned cw = (unsigned)(colsplit + w * 256 + wn * 128 + l15); \
    _Pragma("unroll") \
    for (int m = 0; m < 4; ++m) \
        _Pragma("unroll") \
        for (int j = 0; j < 4; ++j) { \
            const int r = m * 4 + j; \
            _Pragma("unroll") \
            for (int n = 0; n < 8; ++n) { \
                float v = fmaf(-2.f, acc[m][n][j], e2v[n]); \
                unsigned c = cw + n * 16; \
                bool lt1 = v < b1[r], lt2 = v < b2[r]; \
                float nb2 = fminf(fmaxf(v, b1[r]), b2[r]); \
                b1[r] = fminf(v, b1[r]); \
                unsigned pA = (cp[r] << 16) | c; \
                unsigned pB = (cp[r] & 0xFFFFu) | (c << 16); \
                cp[r] = lt1 ? pA : (lt2 ? pB : cp[r]); \
                b2[r] = nb2; \
                acc[m][n][j] = 0.f; \
            } \
        } }

    // prologue: stage g=0 -> buf0, g=1 -> buf1
    STAGE(0, 0);
    STAGE(1, 24576);

    int bb = 0;   // (g%3)*24576, rotated each step
#pragma unroll 1
    for (int g = 0; g < 64; ++g) {
        if (g == 63) { asm volatile("s_waitcnt vmcnt(0)" ::: "memory"); }
        else         { asm volatile("s_waitcnt vmcnt(6)" ::: "memory"); }
        __builtin_amdgcn_s_barrier();
        __builtin_amdgcn_sched_barrier(0);   // pin reads below the barrier only
        half8 ah[4], bh0[4], bh1[4];
#pragma unroll
        for (int m = 0; m < 4; ++m) ah[m] = *(const half8*)(smem + bb + aoff[m]);
#pragma unroll
        for (int n = 0; n < 4; ++n) bh0[n] = *(const half8*)(smem + bb + boff[n]);
        if (g < 62) {   // stage step g+2 into buf (g+2)%3 (continuous ring)
            const int sb = (bb == 0) ? 49152 : bb - 24576;
            STAGE(g + 2, sb);
        }
        // no sched_barrier / setprio here: compiler interleaves MFMAs under the
        // outstanding ds_reads via counted lgkmcnt (the m97 mechanism)
#pragma unroll
        for (int m = 0; m < 4; ++m)
#pragma unroll
            for (int n = 0; n < 4; ++n)
                acc[m][n] = __builtin_amdgcn_mfma_f32_16x16x32_f16(ah[m], bh0[n], acc[m][n], 0, 0, 0);
#pragma unroll
        for (int n = 0; n < 4; ++n) bh1[n] = *(const half8*)(smem + bb + boff[n + 4]);
#pragma unroll
        for (int m = 0; m < 4; ++m)
#pragma unroll
            for (int n = 0; n < 4; ++n)
                acc[m][n + 4] = __builtin_amdgcn_mfma_f32_16x16x32_f16(ah[m], bh1[n], acc[m][n + 4], 0, 0, 0);
        if ((g & 15) == 15) FOLD(g >> 4);
        bb = (bb == 49152) ? 0 : bb + 24576;
    }
#undef STAGE
#undef FOLD

    // ---- once per block: lexicographic (value, idx) butterfly over the 16 col-lanes ----
#pragma unroll
    for (int mask = 1; mask <= 8; mask <<= 1) {
#pragma unroll
        for (int r = 0; r < 16; ++r) {
            float o1 = __shfl_xor(b1[r], mask);
            float o2 = __shfl_xor(b2[r], mask);
            unsigned ocp = __shfl_xor(cp[r], mask);
            unsigned c1 = cp[r] & 0xFFFFu, c2 = cp[r] >> 16;
            unsigned p1 = ocp & 0xFFFFu,   p2 = ocp >> 16;
            bool lt = (o1 < b1[r]) || (o1 == b1[r] && p1 < c1);
            float n1v, n2v; unsigned n1c, n2c;
            if (lt) {
                n1v = o1; n1c = p1;
                bool t = (b1[r] < o2) || (b1[r] == o2 && c1 < p2);
                n2v = t ? b1[r] : o2; n2c = t ? c1 : p2;
            } else {
                n1v = b1[r]; n1c = c1;
                bool t = (o1 < b2[r]) || (o1 == b2[r] && p1 < c2);
                n2v = t ? o1 : b2[r]; n2c = t ? p1 : c2;
            }
            b1[r] = n1v; b2[r] = n2v; cp[r] = n1c | (n2c << 16);
        }
    }

    unsigned long long* mbuf = (unsigned long long*)smem;  // [4][128]
    __syncthreads();   // all K-loop LDS reads done before reuse as mbuf
    if (l15 == 0) {
#pragma unroll
        for (int m = 0; m < 4; ++m)
#pragma unroll
            for (int j = 0; j < 4; ++j) {
                int row = wm * 64 + m * 16 + q * 4 + j;
                int r = m * 4 + j;
                mbuf[(wn * 2 + 0) * 128 + row] = enc64(b1[r], cp[r] & 0xFFFFu);
                mbuf[(wn * 2 + 1) * 128 + row] = enc64(b2[r], cp[r] >> 16);
            }
    }
    __syncthreads();
    if (tid < 128) {   // combine wn-halves -> per-(row, col-group) top-2
        unsigned long long s0 = mbuf[tid],       s1 = mbuf[128 + tid];
        unsigned long long s2 = mbuf[256 + tid], s3 = mbuf[384 + tid];
        unsigned long long t1, t2;
        if (s0 < s2) { t1 = s0; t2 = s1 < s2 ? s1 : s2; }
        else         { t1 = s2; t2 = s3 < s0 ? s3 : s0; }
        pt1[cg * N_ROWS + rowbase + tid] = t1;
        pt2[cg * N_ROWS + rowbase + tid] = t2;
    }
}

// ====== kernel 2: assign = fused merge + gap-gated fp64 refine + quantize + loss + bins ======
__global__ void assign_kernel(const float* __restrict__ x, const float* __restrict__ embed,
                              const unsigned long long* __restrict__ pt1,
                              const unsigned long long* __restrict__ pt2,
                              float* __restrict__ ws, float* __restrict__ out) {
    int tid = threadIdx.x, wid = tid >> 6, lane = tid & 63;
    int row = blockIdx.x * 4 + wid;                 // one wave per row
    const float* xr = x + row * DIM + lane * 8;
    float4 xv0 = *(const float4*)xr;
    float4 xv1 = *(const float4*)(xr + 4);
    float xv[8] = {xv0.x, xv0.y, xv0.z, xv0.w, xv1.x, xv1.y, xv1.z, xv1.w};

    // fused merge: 8 col-group partials x2 -> global top-4 (all lanes redundantly)
    unsigned long long t[4] = {~0ull, ~0ull, ~0ull, ~0ull};
#pragma unroll
    for (int cb = 0; cb < NSPLIT; ++cb) {
        unsigned long long a = pt1[cb * N_ROWS + row];
        unsigned long long b = pt2[cb * N_ROWS + row];
#pragma unroll
        for (int z = 0; z < 2; ++z) {
            unsigned long long v = z ? b : a;
            if (v < t[3]) {
                t[3] = v;
                if (t[3] < t[2]) { unsigned long long y = t[2]; t[2] = t[3]; t[3] = y;
                    if (t[2] < t[1]) { y = t[1]; t[1] = t[2]; t[2] = y;
                        if (t[1] < t[0]) { y = t[0]; t[0] = t[1]; t[1] = y; } } }
            }
        }
    }
    float gap = dec64(t[1]) - dec64(t[0]);
    int besti = (int)(t[0] & 0x1FFFu);
    if (gap <= THRGAP) {   // rare: exact fp64 over 4 candidates
        double bestv = 1e300; besti = 0x7fffffff;
#pragma unroll
        for (int s = 0; s < 4; ++s) {
            int ci = (int)(t[s] & 0x1FFFu);
            const float* er = embed + ci * DIM + lane * 8;
            double d = 0.0;
#pragma unroll
            for (int u = 0; u < 8; ++u) {
                double diff = (double)xv[u] - (double)er[u];
                d += diff * diff;
            }
#pragma unroll
            for (int off = 32; off; off >>= 1) d += __shfl_xor(d, off);
            if (d < bestv || (d == bestv && ci < besti)) { bestv = d; besti = ci; }
        }
    }

    const float* er = embed + besti * DIM + lane * 8;
    float4 q0 = *(const float4*)er;
    float4 q1 = *(const float4*)(er + 4);
    float qv[8] = {q0.x, q0.y, q0.z, q0.w, q1.x, q1.y, q1.z, q1.w};
    float st[8], ls = 0.f;
#pragma unroll
    for (int u = 0; u < 8; ++u) {
        float d = qv[u] - xv[u];
        st[u] = xv[u] + d;          // match ref rounding: x + (q - x)
        ls += d * d;
    }
    float* oq = out + OQ + row * DIM + lane * 8;
    *(float4*)oq       = (float4){st[0], st[1], st[2], st[3]};
    *(float4*)(oq + 4) = (float4){st[4], st[5], st[6], st[7]};
#pragma unroll
    for (int off = 32; off; off >>= 1) ls += __shfl_xor(ls, off);
    __shared__ float lsb[4];
    if (lane == 0) {
        lsb[wid] = ls;
        out[OI + row] = (float)besti;
        ((int*)ws)[WS_IND + row] = besti;
        atomicAdd((int*)ws + WS_BINS + besti, 1);
    }
    __syncthreads();
    if (tid == 0) atomicAdd(ws + WS_LOSS, lsb[0] + lsb[1] + lsb[2] + lsb[3]);
}

// ===== kernel 3: fused cluster + scan (single block): ncs, total, loss, offsets =====
__global__ void scan_kernel(const float* __restrict__ cs, float* __restrict__ ws,
                            float* __restrict__ out) {
    __shared__ int lds[256];
    __shared__ float fl[256];
    int tid = threadIdx.x;
    const int* bins = (const int*)ws + WS_BINS;
    int* off  = (int*)ws + WS_OFF;
    int* woff = (int*)ws + WS_WOFF;
    int base = tid * 32;
    int local[32], s = 0; float sn = 0.f;
#pragma unroll
    for (int j = 0; j < 32; ++j) {
        int b = bins[base + j];
        local[j] = b; s += b;
        float ncs = DECAYF * cs[base + j] + RESIDF * (float)b;
        out[OC + base + j] = ncs;
        sn += ncs;
    }
    lds[tid] = s; fl[tid] = sn;
    __syncthreads();
    for (int o = 1; o < 256; o <<= 1) {   // Hillis-Steele inclusive scan + float total
        int v = (tid >= o) ? lds[tid - o] : 0;
        float f = (tid >= o) ? fl[tid - o] : 0.f;
        __syncthreads();
        lds[tid] += v; fl[tid] += f;
        __syncthreads();
    }
    int run = lds[tid] - s;   // exclusive
#pragma unroll
    for (int j = 0; j < 32; ++j) {
        off[base + j] = run; woff[base + j] = run;
        run += local[j];
    }
    if (tid == 0) {
        ws[WS_TOTAL] = fl[255];
        out[OL] = ws[WS_LOSS] / 8388608.0f;
    }
}

// ===== kernel 4: scatter row ids into code-sorted order (64 blocks, global atomics) =====
__global__ void scatter_kernel(float* __restrict__ ws) {
    int row = blockIdx.x * 256 + threadIdx.x;
    int ind = ((const int*)ws)[WS_IND + row];
    int pos = atomicAdd((int*)ws + WS_WOFF + ind, 1);
    ((int*)ws)[WS_SORTED + pos] = row;
}

// ===== kernel 5: segmented EMA sum + smoothed divide (one wave per code) =====
__global__ void ema_kernel(const float* __restrict__ x, const float* __restrict__ avg,
                           const float* __restrict__ ws, float* __restrict__ out) {
    int tid = threadIdx.x, wid = tid >> 6, lane = tid & 63;
    int k = blockIdx.x * 4 + wid;
    int cnt   = ((const int*)ws)[WS_BINS + k];
    int start = ((const int*)ws)[WS_OFF + k];
    const int c8 = lane * 8;
    float sum[8] = {0.f, 0.f, 0.f, 0.f, 0.f, 0.f, 0.f, 0.f};
    for (int c = 0; c < cnt; ++c) {
        int row = ((const int*)ws)[WS_SORTED + start + c];
        const float* xr = x + row * DIM + c8;
        float4 v0 = *(const float4*)xr;
        float4 v1 = *(const float4*)(xr + 4);
        sum[0] += v0.x; sum[1] += v0.y; sum[2] += v0.z; sum[3] += v0.w;
        sum[4] += v1.x; sum[5] += v1.y; sum[6] += v1.z; sum[7] += v1.w;
    }
    const float* ar = avg + k * DIM + c8;
    float4 a0 = *(const float4*)ar;
    float4 a1 = *(const float4*)(ar + 4);
    float av[8] = {a0.x, a0.y, a0.z, a0.w, a1.x, a1.y, a1.z, a1.w};
    float total = ws[WS_TOTAL];
    float ncs = out[OC + k];
    float sm = (ncs + EPSF) / (total + (float)KCODES * EPSF) * total;
    float* oa = out + OA + k * DIM + c8;   // 4B-aligned regions -> scalar stores
    float* oe = out + OE + k * DIM + c8;
#pragma unroll
    for (int u = 0; u < 8; ++u) {
        float na = DECAYF * av[u] + RESIDF * sum[u];
        oa[u] = na;
        oe[u] = na / sm;
    }
}

extern "C" void kernel_launch(void* const* d_in, const int* in_sizes, int n_in,
                              void* d_out, int out_size, void* d_ws, size_t ws_size,
                              hipStream_t stream) {
    const float* x     = (const float*)d_in[0];
    const float* embed = (const float*)d_in[1];
    const float* cs    = (const float*)d_in[2];
    const float* avg   = (const float*)d_in[3];
    float* out = (float*)d_out;
    float* ws  = (float*)d_ws;

    // fp16/partial scratch inside d_out (each region consumed before final write):
    //   Xs (16.8MB) in OQ; Es (8.39MB) in OE first half; pt1 (1MB) after Es;
    //   pt2 (1MB) in OA. assign consumes pt1/pt2 before ema writes OE/OA.
    _Float16* xs = (_Float16*)((char*)d_out + (size_t)OQ * 4);
    char* esb = (char*)d_out + (((size_t)OE * 4 + 15) & ~(size_t)15);
    _Float16* es = (_Float16*)esb;
    unsigned long long* pt1 = (unsigned long long*)(esb + (size_t)KCODES * DIM * 2);
    unsigned long long* pt2 =
        (unsigned long long*)((char*)d_out + (((size_t)OA * 4 + 15) & ~(size_t)15));

    // zero bins + loss + total each call
    hipMemsetAsync((char*)d_ws + WS_BINS * 4, 0, (8192 + 2) * 4, stream);

    convxe_kernel <<<6144, 256, 0, stream>>>(x, embed, xs, es, ws);
    dist_kernel   <<<1024, 256, 0, stream>>>(xs, es, ws, pt1, pt2);
    assign_kernel <<<N_ROWS / 4, 256, 0, stream>>>(x, embed, pt1, pt2, ws, out);
    scan_kernel   <<<1, 256, 0, stream>>>(cs, ws, out);
    scatter_kernel<<<N_ROWS / 256, 256, 0, stream>>>(ws);
    ema_kernel    <<<KCODES / 4, 256, 0, stream>>>(x, avg, ws, out);
}

// Round 19
// 333.101 us; speedup vs baseline: 1.3406x; 1.1393x over previous
//
#include <hip/hip_runtime.h>

// Problem constants (fixed shapes for this identifier)
#define N_ROWS 16384   // b*n = 4*4096
#define DIM    512
#define KCODES 8192

#define DECAYF 0.8f
#define RESIDF 0.2f
#define EPSF   1e-5f
#define THRGAP 0.15f   // refine-skip threshold (~8 sigma of 1-pass fp16 score noise)
#define NSPLIT 8       // col-groups per row (1024 cols each)

// ---- d_out float offsets (outputs concatenated in return order) ----
#define OQ 0            // quantize_st    [16384,512]  (scratch: Xs fp16)
#define OI 8388608      // ind            [16384]
#define OL 8404992      // commit_loss    [1]
#define OE 8404993      // new_embed      [8192,512]   (scratch: Es fp16 + pt1)
#define OC 12599297     // new_cluster    [8192]
#define OA 12607489     // new_embed_avg  [8192,512]   (scratch: pt2)

// ---- workspace offsets (float-indexed; int arrays alias) ----
#define WS_E2     0                    // [8192] float
#define WS_BINS   8192                 // [8192] int counts (zeroed by convxe blocks 0-31)
#define WS_IND    16400                // [16384] int final index
#define WS_OFF    (WS_IND+16384)       // [8192] int exclusive offsets
#define WS_WOFF   (WS_OFF+8192)        // [8192] int working offsets (scatter)
#define WS_SORTED (WS_WOFF+8192)       // [16384] int row ids sorted by code
#define WS_TOTAL  (WS_SORTED+16384)    // [1] float
#define WS_LOSSP  (WS_TOTAL+16)        // [4096] float per-block loss partials

typedef _Float16 half8 __attribute__((ext_vector_type(8)));
typedef float f32x4 __attribute__((ext_vector_type(4)));

__device__ __forceinline__ void ldg_lds16(const char* g, char* l) {
    __builtin_amdgcn_global_load_lds(
        (const __attribute__((address_space(1))) void*)g,
        (__attribute__((address_space(3))) void*)l, 16, 0, 0);
}

// monotonic (score,idx) -> u64: order-preserving, ties break to smaller idx
__device__ __forceinline__ unsigned long long enc64(float v, unsigned idx) {
    unsigned int b = __float_as_uint(v);
    b ^= (unsigned)((int)b >> 31) | 0x80000000u;
    return ((unsigned long long)b << 13) | idx;
}
__device__ __forceinline__ float dec64(unsigned long long u) {
    unsigned int eb = (unsigned int)(u >> 13);
    unsigned int b = (eb & 0x80000000u) ? (eb ^ 0x80000000u) : ~eb;
    return __uint_as_float(b);
}

// ======= kernel 0: fused x->Xs fp16, embed->Es fp16 + e2, and bins zeroing =======
__global__ void convxe_kernel(const float* __restrict__ x, const float* __restrict__ e,
                              _Float16* __restrict__ xs, _Float16* __restrict__ es,
                              float* __restrict__ ws) {
    if (blockIdx.x < 32)   // zero bins (8192 ints = 32 x 256); replaces hipMemsetAsync
        ((int*)ws)[WS_BINS + blockIdx.x * 256 + threadIdx.x] = 0;
    if (blockIdx.x < 4096) {
        int i = blockIdx.x * 256 + threadIdx.x;
        int row = i >> 6;
        int c8 = (i & 63) * 8;
        const float4* g = (const float4*)(x + row * DIM + c8);
        float4 v0 = g[0], v1 = g[1];
        float vv[8] = {v0.x, v0.y, v0.z, v0.w, v1.x, v1.y, v1.z, v1.w};
        half8 hv;
#pragma unroll
        for (int j = 0; j < 8; ++j) hv[j] = (_Float16)vv[j];
        *(half8*)(xs + row * DIM + c8) = hv;
    } else {
        int i = (blockIdx.x - 4096) * 256 + threadIdx.x;   // one wave per code row
        int row = i >> 6;
        int lane = threadIdx.x & 63;
        int c8 = (i & 63) * 8;
        const float4* g = (const float4*)(e + row * DIM + c8);
        float4 v0 = g[0], v1 = g[1];
        float vv[8] = {v0.x, v0.y, v0.z, v0.w, v1.x, v1.y, v1.z, v1.w};
        half8 hv;
        float s = 0.f;
#pragma unroll
        for (int j = 0; j < 8; ++j) { hv[j] = (_Float16)vv[j]; s += vv[j] * vv[j]; }
        *(half8*)(es + row * DIM + c8) = hv;
#pragma unroll
        for (int off = 32; off; off >>= 1) s += __shfl_xor(s, off);
        if (lane == 0) ws[WS_E2 + row] = s;
    }
}

// ============ kernel 1: 1-pass fp16 MFMA distance GEMM (R17, converged at 228us) ============
__global__ __launch_bounds__(256, 2) void dist_kernel(
        const _Float16* __restrict__ xs, const _Float16* __restrict__ es,
        const float* __restrict__ ws,
        unsigned long long* __restrict__ pt1, unsigned long long* __restrict__ pt2) {
    __shared__ __align__(16) char smem[73728];   // 3 x (8KB A | 16KB B)
    __shared__ __align__(16) float e2s[1024];

    const int tid = threadIdx.x, wid = tid >> 6, lane = tid & 63;
    const int xcd = blockIdx.x & 7, i = blockIdx.x >> 3;
    const int rtl = i & 15;                 // row-tile within XCD slice
    const int cg2 = i >> 4;                 // 0..7 col-group (1024 cols)
    const int rowbase = xcd * 2048 + rtl * 128;
    const int colsplit = cg2 * 1024;

    const int wm = wid >> 1, wn = wid & 1;
    const int l15 = lane & 15, q = lane >> 4;
    const int swz = ((q ^ ((l15 >> 1) & 3)) << 4);

    int aoff[4], boff[8];
#pragma unroll
    for (int m = 0; m < 4; ++m) aoff[m] = (wm * 64 + m * 16 + l15) * 64 + swz;
#pragma unroll
    for (int n = 0; n < 8; ++n) boff[n] = 8192 + (wn * 128 + n * 16 + l15) * 64 + swz;

    unsigned gA[2], gB[4];
#pragma unroll
    for (int c = 0; c < 2; ++c) {
        int p = c * 4096 + tid * 16;
        int r = p >> 6, sp = (p >> 4) & 3;
        int sl = sp ^ ((r >> 1) & 3);
        gA[c] = (unsigned)(rowbase + r) * 1024u + (unsigned)(sl * 16);
    }
#pragma unroll
    for (int c = 0; c < 4; ++c) {
        int p = c * 4096 + tid * 16;
        int r = p >> 6, sp = (p >> 4) & 3;
        int sl = sp ^ ((r >> 1) & 3);
        gB[c] = (unsigned)(colsplit + r) * 1024u + (unsigned)(sl * 16);
    }
    const char* xb = (const char*)xs;
    const char* eb = (const char*)es;

    {
        float4 v = *(const float4*)(ws + WS_E2 + colsplit + tid * 4);
        *(float4*)(e2s + tid * 4) = v;
    }
    __syncthreads();

    float b1[16], b2[16]; unsigned cp[16];
#pragma unroll
    for (int r = 0; r < 16; ++r) { b1[r] = 3.4e38f; b2[r] = 3.4e38f; cp[r] = 0xFFFFFFFFu; }

    f32x4 acc[4][8];
#pragma unroll
    for (int m = 0; m < 4; ++m)
#pragma unroll
        for (int n = 0; n < 8; ++n) acc[m][n] = (f32x4){0.f, 0.f, 0.f, 0.f};

#define STAGE(gs_, sb_) { \
    const unsigned koff = ((unsigned)((gs_) & 15)) << 6; \
    const char* ebw = eb + ((size_t)((gs_) >> 4) << 18); \
    _Pragma("unroll") \
    for (int c = 0; c < 2; ++c) \
        ldg_lds16(xb + gA[c] + koff, smem + (sb_) + c * 4096 + (wid << 10)); \
    _Pragma("unroll") \
    for (int c = 0; c < 4; ++c) \
        ldg_lds16(ebw + gB[c] + koff, smem + (sb_) + 8192 + c * 4096 + (wid << 10)); }

#define FOLD(w_) { \
    const int w = (w_); \
    float e2v[8]; \
    _Pragma("unroll") \
    for (int n = 0; n < 8; ++n) e2v[n] = e2s[w * 256 + wn * 128 + n * 16 + l15]; \
    const unsigned cw = (unsigned)(colsplit + w * 256 + wn * 128 + l15); \
    _Pragma("unroll") \
    for (int m = 0; m < 4; ++m) \
        _Pragma("unroll") \
        for (int j = 0; j < 4; ++j) { \
            const int r = m * 4 + j; \
            _Pragma("unroll") \
            for (int n = 0; n < 8; ++n) { \
                float v = fmaf(-2.f, acc[m][n][j], e2v[n]); \
                unsigned c = cw + n * 16; \
                bool lt1 = v < b1[r], lt2 = v < b2[r]; \
                float nb2 = fminf(fmaxf(v, b1[r]), b2[r]); \
                b1[r] = fminf(v, b1[r]); \
                unsigned pA = (cp[r] << 16) | c; \
                unsigned pB = (cp[r] & 0xFFFFu) | (c << 16); \
                cp[r] = lt1 ? pA : (lt2 ? pB : cp[r]); \
                b2[r] = nb2; \
                acc[m][n][j] = 0.f; \
            } \
        } }

    STAGE(0, 0);
    STAGE(1, 24576);

    int bb = 0;
#pragma unroll 1
    for (int g = 0; g < 64; ++g) {
        if (g == 63) { asm volatile("s_waitcnt vmcnt(0)" ::: "memory"); }
        else         { asm volatile("s_waitcnt vmcnt(6)" ::: "memory"); }
        __builtin_amdgcn_s_barrier();
        __builtin_amdgcn_sched_barrier(0);   // pin reads below the barrier only
        half8 ah[4], bh0[4], bh1[4];
#pragma unroll
        for (int m = 0; m < 4; ++m) ah[m] = *(const half8*)(smem + bb + aoff[m]);
#pragma unroll
        for (int n = 0; n < 4; ++n) bh0[n] = *(const half8*)(smem + bb + boff[n]);
        if (g < 62) {
            const int sb = (bb == 0) ? 49152 : bb - 24576;
            STAGE(g + 2, sb);
        }
#pragma unroll
        for (int m = 0; m < 4; ++m)
#pragma unroll
            for (int n = 0; n < 4; ++n)
                acc[m][n] = __builtin_amdgcn_mfma_f32_16x16x32_f16(ah[m], bh0[n], acc[m][n], 0, 0, 0);
#pragma unroll
        for (int n = 0; n < 4; ++n) bh1[n] = *(const half8*)(smem + bb + boff[n + 4]);
#pragma unroll
        for (int m = 0; m < 4; ++m)
#pragma unroll
            for (int n = 0; n < 4; ++n)
                acc[m][n + 4] = __builtin_amdgcn_mfma_f32_16x16x32_f16(ah[m], bh1[n], acc[m][n + 4], 0, 0, 0);
        if ((g & 15) == 15) FOLD(g >> 4);
        bb = (bb == 49152) ? 0 : bb + 24576;
    }
#undef STAGE
#undef FOLD

#pragma unroll
    for (int mask = 1; mask <= 8; mask <<= 1) {
#pragma unroll
        for (int r = 0; r < 16; ++r) {
            float o1 = __shfl_xor(b1[r], mask);
            float o2 = __shfl_xor(b2[r], mask);
            unsigned ocp = __shfl_xor(cp[r], mask);
            unsigned c1 = cp[r] & 0xFFFFu, c2 = cp[r] >> 16;
            unsigned p1 = ocp & 0xFFFFu,   p2 = ocp >> 16;
            bool lt = (o1 < b1[r]) || (o1 == b1[r] && p1 < c1);
            float n1v, n2v; unsigned n1c, n2c;
            if (lt) {
                n1v = o1; n1c = p1;
                bool t = (b1[r] < o2) || (b1[r] == o2 && c1 < p2);
                n2v = t ? b1[r] : o2; n2c = t ? c1 : p2;
            } else {
                n1v = b1[r]; n1c = c1;
                bool t = (o1 < b2[r]) || (o1 == b2[r] && p1 < c2);
                n2v = t ? o1 : b2[r]; n2c = t ? p1 : c2;
            }
            b1[r] = n1v; b2[r] = n2v; cp[r] = n1c | (n2c << 16);
        }
    }

    unsigned long long* mbuf = (unsigned long long*)smem;  // [4][128]
    __syncthreads();
    if (l15 == 0) {
#pragma unroll
        for (int m = 0; m < 4; ++m)
#pragma unroll
            for (int j = 0; j < 4; ++j) {
                int row = wm * 64 + m * 16 + q * 4 + j;
                int r = m * 4 + j;
                mbuf[(wn * 2 + 0) * 128 + row] = enc64(b1[r], cp[r] & 0xFFFFu);
                mbuf[(wn * 2 + 1) * 128 + row] = enc64(b2[r], cp[r] >> 16);
            }
    }
    __syncthreads();
    if (tid < 128) {
        unsigned long long s0 = mbuf[tid],       s1 = mbuf[128 + tid];
        unsigned long long s2 = mbuf[256 + tid], s3 = mbuf[384 + tid];
        unsigned long long t1, t2;
        if (s0 < s2) { t1 = s0; t2 = s1 < s2 ? s1 : s2; }
        else         { t1 = s2; t2 = s3 < s0 ? s3 : s0; }
        pt1[cg2 * N_ROWS + rowbase + tid] = t1;
        pt2[cg2 * N_ROWS + rowbase + tid] = t2;
    }
}

// ====== kernel 2: assign = fused merge + gap-gated fp64 refine + quantize + loss + bins ======
__global__ void assign_kernel(const float* __restrict__ x, const float* __restrict__ embed,
                              const unsigned long long* __restrict__ pt1,
                              const unsigned long long* __restrict__ pt2,
                              float* __restrict__ ws, float* __restrict__ out) {
    int tid = threadIdx.x, wid = tid >> 6, lane = tid & 63;
    int row = blockIdx.x * 4 + wid;                 // one wave per row
    const float* xr = x + row * DIM + lane * 8;
    float4 xv0 = *(const float4*)xr;
    float4 xv1 = *(const float4*)(xr + 4);
    float xv[8] = {xv0.x, xv0.y, xv0.z, xv0.w, xv1.x, xv1.y, xv1.z, xv1.w};

    // fused merge: 8 col-group partials x2 -> global top-4 (all lanes redundantly)
    unsigned long long t[4] = {~0ull, ~0ull, ~0ull, ~0ull};
#pragma unroll
    for (int cb = 0; cb < NSPLIT; ++cb) {
        unsigned long long a = pt1[cb * N_ROWS + row];
        unsigned long long b = pt2[cb * N_ROWS + row];
#pragma unroll
        for (int z = 0; z < 2; ++z) {
            unsigned long long v = z ? b : a;
            if (v < t[3]) {
                t[3] = v;
                if (t[3] < t[2]) { unsigned long long y = t[2]; t[2] = t[3]; t[3] = y;
                    if (t[2] < t[1]) { y = t[1]; t[1] = t[2]; t[2] = y;
                        if (t[1] < t[0]) { y = t[0]; t[0] = t[1]; t[1] = y; } } }
            }
        }
    }
    float gap = dec64(t[1]) - dec64(t[0]);
    int besti = (int)(t[0] & 0x1FFFu);
    if (gap <= THRGAP) {   // rare: exact fp64 over 4 candidates
        double bestv = 1e300; besti = 0x7fffffff;
#pragma unroll
        for (int s = 0; s < 4; ++s) {
            int ci = (int)(t[s] & 0x1FFFu);
            const float* er = embed + ci * DIM + lane * 8;
            double d = 0.0;
#pragma unroll
            for (int u = 0; u < 8; ++u) {
                double diff = (double)xv[u] - (double)er[u];
                d += diff * diff;
            }
#pragma unroll
            for (int off = 32; off; off >>= 1) d += __shfl_xor(d, off);
            if (d < bestv || (d == bestv && ci < besti)) { bestv = d; besti = ci; }
        }
    }

    const float* er = embed + besti * DIM + lane * 8;
    float4 q0 = *(const float4*)er;
    float4 q1 = *(const float4*)(er + 4);
    float qv[8] = {q0.x, q0.y, q0.z, q0.w, q1.x, q1.y, q1.z, q1.w};
    float st[8], ls = 0.f;
#pragma unroll
    for (int u = 0; u < 8; ++u) {
        float d = qv[u] - xv[u];
        st[u] = xv[u] + d;          // match ref rounding: x + (q - x)
        ls += d * d;
    }
    float* oq = out + OQ + row * DIM + lane * 8;
    *(float4*)oq       = (float4){st[0], st[1], st[2], st[3]};
    *(float4*)(oq + 4) = (float4){st[4], st[5], st[6], st[7]};
#pragma unroll
    for (int off = 32; off; off >>= 1) ls += __shfl_xor(ls, off);
    __shared__ float lsb[4];
    if (lane == 0) {
        lsb[wid] = ls;
        out[OI + row] = (float)besti;
        ((int*)ws)[WS_IND + row] = besti;
        atomicAdd((int*)ws + WS_BINS + besti, 1);
    }
    __syncthreads();
    if (tid == 0) ws[WS_LOSSP + blockIdx.x] = lsb[0] + lsb[1] + lsb[2] + lsb[3];
}

// ===== kernel 3: fused loss finalize + cluster + scan (single block) =====
__global__ void scan_kernel(const float* __restrict__ cs, float* __restrict__ ws,
                            float* __restrict__ out) {
    __shared__ int lds[256];
    __shared__ float fl[256];
    __shared__ float lsb[4];
    int tid = threadIdx.x, wid = tid >> 6, lane = tid & 63;

    // loss: sum 4096 per-block partials (16 per thread)
    float lp = 0.f;
#pragma unroll
    for (int j = 0; j < 16; ++j) lp += ws[WS_LOSSP + tid * 16 + j];
#pragma unroll
    for (int off = 32; off; off >>= 1) lp += __shfl_xor(lp, off);
    if (lane == 0) lsb[wid] = lp;

    const int* bins = (const int*)ws + WS_BINS;
    int* off  = (int*)ws + WS_OFF;
    int* woff = (int*)ws + WS_WOFF;
    int base = tid * 32;
    int local[32], s = 0; float sn = 0.f;
#pragma unroll
    for (int j = 0; j < 32; ++j) {
        int b = bins[base + j];
        local[j] = b; s += b;
        float ncs = DECAYF * cs[base + j] + RESIDF * (float)b;
        out[OC + base + j] = ncs;
        sn += ncs;
    }
    lds[tid] = s; fl[tid] = sn;
    __syncthreads();
    if (tid == 0) out[OL] = (lsb[0] + lsb[1] + lsb[2] + lsb[3]) / 8388608.0f;
    for (int o = 1; o < 256; o <<= 1) {   // Hillis-Steele inclusive scan + float total
        int v = (tid >= o) ? lds[tid - o] : 0;
        float f = (tid >= o) ? fl[tid - o] : 0.f;
        __syncthreads();
        lds[tid] += v; fl[tid] += f;
        __syncthreads();
    }
    int run = lds[tid] - s;   // exclusive
#pragma unroll
    for (int j = 0; j < 32; ++j) {
        off[base + j] = run; woff[base + j] = run;
        run += local[j];
    }
    if (tid == 0) ws[WS_TOTAL] = fl[255];
}

// ===== kernel 4: scatter row ids into code-sorted order (64 blocks, global atomics) =====
__global__ void scatter_kernel(float* __restrict__ ws) {
    int row = blockIdx.x * 256 + threadIdx.x;
    int ind = ((const int*)ws)[WS_IND + row];
    int pos = atomicAdd((int*)ws + WS_WOFF + ind, 1);
    ((int*)ws)[WS_SORTED + pos] = row;
}

// ===== kernel 5: segmented EMA sum + smoothed divide (one wave per code) =====
__global__ void ema_kernel(const float* __restrict__ x, const float* __restrict__ avg,
                           const float* __restrict__ ws, float* __restrict__ out) {
    int tid = threadIdx.x, wid = tid >> 6, lane = tid & 63;
    int k = blockIdx.x * 4 + wid;
    int cnt   = ((const int*)ws)[WS_BINS + k];
    int start = ((const int*)ws)[WS_OFF + k];
    const int c8 = lane * 8;
    float sum[8] = {0.f, 0.f, 0.f, 0.f, 0.f, 0.f, 0.f, 0.f};
    for (int c = 0; c < cnt; ++c) {
        int row = ((const int*)ws)[WS_SORTED + start + c];
        const float* xr = x + row * DIM + c8;
        float4 v0 = *(const float4*)xr;
        float4 v1 = *(const float4*)(xr + 4);
        sum[0] += v0.x; sum[1] += v0.y; sum[2] += v0.z; sum[3] += v0.w;
        sum[4] += v1.x; sum[5] += v1.y; sum[6] += v1.z; sum[7] += v1.w;
    }
    const float* ar = avg + k * DIM + c8;
    float4 a0 = *(const float4*)ar;
    float4 a1 = *(const float4*)(ar + 4);
    float av[8] = {a0.x, a0.y, a0.z, a0.w, a1.x, a1.y, a1.z, a1.w};
    float total = ws[WS_TOTAL];
    float ncs = out[OC + k];
    float sm = (ncs + EPSF) / (total + (float)KCODES * EPSF) * total;
    float* oa = out + OA + k * DIM + c8;   // 4B-aligned regions -> scalar stores
    float* oe = out + OE + k * DIM + c8;
#pragma unroll
    for (int u = 0; u < 8; ++u) {
        float na = DECAYF * av[u] + RESIDF * sum[u];
        oa[u] = na;
        oe[u] = na / sm;
    }
}

extern "C" void kernel_launch(void* const* d_in, const int* in_sizes, int n_in,
                              void* d_out, int out_size, void* d_ws, size_t ws_size,
                              hipStream_t stream) {
    const float* x     = (const float*)d_in[0];
    const float* embed = (const float*)d_in[1];
    const float* cs    = (const float*)d_in[2];
    const float* avg   = (const float*)d_in[3];
    float* out = (float*)d_out;
    float* ws  = (float*)d_ws;

    // fp16/partial scratch inside d_out (each region consumed before final write):
    //   Xs (16.8MB) in OQ; Es (8.39MB) in OE first half; pt1 (1MB) after Es;
    //   pt2 (1MB) in OA. assign consumes pt1/pt2 before ema writes OE/OA.
    _Float16* xs = (_Float16*)((char*)d_out + (size_t)OQ * 4);
    char* esb = (char*)d_out + (((size_t)OE * 4 + 15) & ~(size_t)15);
    _Float16* es = (_Float16*)esb;
    unsigned long long* pt1 = (unsigned long long*)(esb + (size_t)KCODES * DIM * 2);
    unsigned long long* pt2 =
        (unsigned long long*)((char*)d_out + (((size_t)OA * 4 + 15) & ~(size_t)15));

    convxe_kernel <<<6144, 256, 0, stream>>>(x, embed, xs, es, ws);
    dist_kernel   <<<1024, 256, 0, stream>>>(xs, es, ws, pt1, pt2);
    assign_kernel <<<N_ROWS / 4, 256, 0, stream>>>(x, embed, pt1, pt2, ws, out);
    scan_kernel   <<<1, 256, 0, stream>>>(cs, ws, out);
    scatter_kernel<<<N_ROWS / 256, 256, 0, stream>>>(ws);
    ema_kernel    <<<KCODES / 4, 256, 0, stream>>>(x, avg, ws, out);
}